// Round 2
// baseline (547.282 us; speedup 1.0000x reference)
//
#include <hip/hip_runtime.h>
#include <hip/hip_bf16.h>

typedef __hip_bfloat16 bf16;

// Dims
constexpr int cD0 = 24,  cH0 = 64,  cW0 = 128;   // cv1 / x1 spatial
constexpr int cD1 = 48,  cH1 = 128, cW1 = 256;   // x2 / cv0 / x3 spatial
constexpr int cD2 = 96,  cH2 = 256, cW2 = 512;   // cost / out spatial
constexpr size_t PL0 = (size_t)cD0 * cH0 * cW0;  // 196608  per-channel plane
constexpr size_t PL1 = (size_t)cD1 * cH1 * cW1;  // 1572864
constexpr size_t PL2 = (size_t)cD2 * cH2 * cW2;  // 12582912

__device__ __forceinline__ float b2f(bf16 v) { return __bfloat162float(v); }
__device__ __forceinline__ bf16  f2b(float v) { return __float2bfloat16(v); }
__device__ __forceinline__ float lrelu(float v) { return v >= 0.f ? v : 0.01f * v; }

// ---------------- Stage A: x1 = bn_lrelu(deconv(cv1, w0a, s1, pad(1,0,0))) ----
// x1[co,z,y,x] = lrelu(scale0[co]*Sum_{ci,u} w0a[ci,co,u]*cv1[ci,z+1-u,y,x] + b0[co])
__global__ __launch_bounds__(256) void kA(const float* __restrict__ cv1,
                                          const float* __restrict__ w0a,
                                          const float* __restrict__ g0,
                                          const float* __restrict__ b0,
                                          bf16* __restrict__ x1) {
    __shared__ float lw[3][32][32];   // [u][ci][co], co contiguous for float4
    __shared__ float lsc[32], lbi[32];
    const int tid = threadIdx.x;
    for (int i = tid; i < 32 * 32 * 3; i += 256) {
        int ci = i / 96, r = i - ci * 96, co = r / 3, u = r - co * 3;
        lw[u][ci][co] = w0a[i];
    }
    if (tid < 32) {
        lsc[tid] = g0[tid] * (1.0f / sqrtf(1.0f + 1e-5f));
        lbi[tid] = b0[tid];
    }
    __syncthreads();

    const int pos = blockIdx.x * 256 + tid;        // 196608 total
    const int x = pos & (cW0 - 1);
    const int y = (pos >> 7) & (cH0 - 1);
    const int z = pos >> 13;

    float acc[32];
    #pragma unroll
    for (int co = 0; co < 32; ++co) acc[co] = 0.f;

    #pragma unroll
    for (int u = 0; u < 3; ++u) {
        const int zi = z + 1 - u;
        if (zi < 0 || zi >= cD0) continue;
        const float* src = cv1 + (size_t)(zi * cH0 + y) * cW0 + x;
        for (int ci = 0; ci < 32; ++ci) {
            const float v = src[ci * PL0];
            const float4* wp = (const float4*)&lw[u][ci][0];
            #pragma unroll
            for (int q = 0; q < 8; ++q) {
                float4 wv = wp[q];
                acc[4*q+0] += v * wv.x; acc[4*q+1] += v * wv.y;
                acc[4*q+2] += v * wv.z; acc[4*q+3] += v * wv.w;
            }
        }
    }
    #pragma unroll
    for (int co = 0; co < 32; ++co)
        x1[co * PL0 + (size_t)(z * cH0 + y) * cW0 + x] =
            f2b(lrelu(acc[co] * lsc[co] + lbi[co]));
}

// ---------------- Stage B: x2 = bn_lrelu(deconv(x1, w0b, s2, pad(1,0,0))) ----
// x2[co,od,oh,ow] = Sum_{ci, kd in parity set} w0b[ci,co,kd,oh&1,ow&1] * x1[ci,(od+1-kd)/2,oh>>1,ow>>1]
__global__ __launch_bounds__(256) void kB(const bf16* __restrict__ x1,
                                          const float* __restrict__ w0b,
                                          const float* __restrict__ g1,
                                          const float* __restrict__ b1,
                                          bf16* __restrict__ x2) {
    __shared__ float lw[4][2][2][32][16];   // [kd][kh][kw][ci][co]
    __shared__ float lsc[16], lbi[16];
    const int tid = threadIdx.x;
    for (int i = tid; i < 8192; i += 256) {
        // source layout (ci,co,kd,kh,kw): i = ci*256 + co*16 + kd*4 + kh*2 + kw
        int ci = i >> 8, co = (i >> 4) & 15, kd = (i >> 2) & 3, kh = (i >> 1) & 1, kw = i & 1;
        lw[kd][kh][kw][ci][co] = w0b[i];
    }
    if (tid < 16) {
        lsc[tid] = g1[tid] * (1.0f / sqrtf(1.0f + 1e-5f));
        lbi[tid] = b1[tid];
    }
    __syncthreads();

    const int pos = blockIdx.x * 256 + tid;        // 1572864 total
    const int ow = pos & 255, oh = (pos >> 8) & 127, od = pos >> 15;
    const int iw = ow >> 1, kw = ow & 1, ih = oh >> 1, kh = oh & 1;
    const int p = (od + 1) & 1;

    float acc[16];
    #pragma unroll
    for (int co = 0; co < 16; ++co) acc[co] = 0.f;

    #pragma unroll
    for (int j = 0; j < 2; ++j) {
        const int kd = p + 2 * j;
        const int id = (od + 1 - kd) >> 1;
        if (id < 0 || id >= cD0) continue;
        const bf16* src = x1 + (size_t)(id * cH0 + ih) * cW0 + iw;
        const float4* wbase = (const float4*)&lw[kd][kh][kw][0][0];
        for (int ci = 0; ci < 32; ++ci) {
            const float v = b2f(src[ci * PL0]);
            #pragma unroll
            for (int q = 0; q < 4; ++q) {
                float4 wv = wbase[ci * 4 + q];
                acc[4*q+0] += v * wv.x; acc[4*q+1] += v * wv.y;
                acc[4*q+2] += v * wv.z; acc[4*q+3] += v * wv.w;
            }
        }
    }
    #pragma unroll
    for (int co = 0; co < 16; ++co)
        x2[co * PL1 + (size_t)(od * cH1 + oh) * cW1 + ow] =
            f2b(lrelu(acc[co] * lsc[co] + lbi[co]));
}

// ---------------- Stage D: x3 = bn_lrelu(deconv(concat(x2,cv0), w1a, s1, pad(1,0,0)))
__global__ __launch_bounds__(256) void kD(const bf16* __restrict__ x2,
                                          const float* __restrict__ cv0,
                                          const float* __restrict__ w1a,
                                          const float* __restrict__ g2,
                                          const float* __restrict__ b2v,
                                          bf16* __restrict__ x3) {
    __shared__ float lw[3][32][16];   // [u][ci][co]
    __shared__ float lsc[16], lbi[16];
    const int tid = threadIdx.x;
    for (int i = tid; i < 1536; i += 256) {
        int ci = i / 48, r = i - ci * 48, co = r / 3, u = r - co * 3;
        lw[u][ci][co] = w1a[i];
    }
    if (tid < 16) {
        lsc[tid] = g2[tid] * (1.0f / sqrtf(1.0f + 1e-5f));
        lbi[tid] = b2v[tid];
    }
    __syncthreads();

    const int pos = blockIdx.x * 256 + tid;        // 1572864 total
    const int x = pos & 255, y = (pos >> 8) & 127, z = pos >> 15;

    float acc[16];
    #pragma unroll
    for (int co = 0; co < 16; ++co) acc[co] = 0.f;

    #pragma unroll
    for (int u = 0; u < 3; ++u) {
        const int zi = z + 1 - u;
        if (zi < 0 || zi >= cD1) continue;
        const size_t base = (size_t)(zi * cH1 + y) * cW1 + x;
        for (int ci = 0; ci < 16; ++ci) {           // channels 0..15 = x2
            const float v = b2f(x2[ci * PL1 + base]);
            const float4* wp = (const float4*)&lw[u][ci][0];
            #pragma unroll
            for (int q = 0; q < 4; ++q) {
                float4 wv = wp[q];
                acc[4*q+0] += v * wv.x; acc[4*q+1] += v * wv.y;
                acc[4*q+2] += v * wv.z; acc[4*q+3] += v * wv.w;
            }
        }
        for (int ci = 0; ci < 16; ++ci) {           // channels 16..31 = cv0
            const float v = cv0[ci * PL1 + base];
            const float4* wp = (const float4*)&lw[u][16 + ci][0];
            #pragma unroll
            for (int q = 0; q < 4; ++q) {
                float4 wv = wp[q];
                acc[4*q+0] += v * wv.x; acc[4*q+1] += v * wv.y;
                acc[4*q+2] += v * wv.z; acc[4*q+3] += v * wv.w;
            }
        }
    }
    #pragma unroll
    for (int co = 0; co < 16; ++co)
        x3[co * PL1 + (size_t)(z * cH1 + y) * cW1 + x] =
            f2b(lrelu(acc[co] * lsc[co] + lbi[co]));
}

// ---------------- Stage E: cost = bn_lrelu(deconv(x3, w1b, s2, pad(1,0,0))) ----
__global__ __launch_bounds__(256) void kE(const bf16* __restrict__ x3,
                                          const float* __restrict__ w1b,
                                          const float* __restrict__ g3,
                                          const float* __restrict__ b3v,
                                          bf16* __restrict__ cost) {
    __shared__ float lw[256];   // w1b (16,1,4,2,2): i = ci*16 + kd*4 + kh*2 + kw
    const int tid = threadIdx.x;
    lw[tid] = w1b[tid];
    __syncthreads();

    const int pos = blockIdx.x * 256 + tid;        // 12582912 total
    const int ow = pos & 511, oh = (pos >> 9) & 255, od = pos >> 17;
    const int iw = ow >> 1, kw = ow & 1, ih = oh >> 1, kh = oh & 1;
    const int p = (od + 1) & 1;

    float acc = 0.f;
    #pragma unroll
    for (int j = 0; j < 2; ++j) {
        const int kd = p + 2 * j;
        const int id = (od + 1 - kd) >> 1;
        if (id < 0 || id >= cD1) continue;
        const size_t base = (size_t)(id * cH1 + ih) * cW1 + iw;
        #pragma unroll
        for (int ci = 0; ci < 16; ++ci)
            acc += b2f(x3[ci * PL1 + base]) * lw[ci * 16 + kd * 4 + kh * 2 + kw];
    }
    const float sc = g3[0] * (1.0f / sqrtf(1.0f + 1e-5f));
    const float bi = b3v[0];
    cost[pos] = f2b(lrelu(acc * sc + bi));
}

// ---------------- Stage F: 9-shift superpixel aggregation --------------------
// out[d,y,x] = Sum_k sp[k,y,x] * cost[d, y-4*hy_k, x-4*wx_k], OOB -> 0
// k = r*3+c with hy = 1-r in (1,0,-1), wx = 1-c in (1,0,-1)
__global__ __launch_bounds__(256) void kF(const bf16* __restrict__ cost,
                                          const float* __restrict__ sp,
                                          float* __restrict__ out) {
    const int pos = blockIdx.x * 256 + threadIdx.x;  // 12582912 total
    const int x = pos & 511, y = (pos >> 9) & 255, d = pos >> 17;
    const size_t plane = (size_t)cH2 * cW2;

    float acc = 0.f;
    #pragma unroll
    for (int r = 0; r < 3; ++r) {
        const int cy = y - 4 * (1 - r);
        if (cy < 0 || cy >= cH2) continue;
        #pragma unroll
        for (int c = 0; c < 3; ++c) {
            const int cx = x - 4 * (1 - c);
            if (cx < 0 || cx >= cW2) continue;
            acc += sp[(size_t)(r * 3 + c) * plane + (size_t)y * cW2 + x] *
                   b2f(cost[(size_t)d * plane + (size_t)cy * cW2 + cx]);
        }
    }
    out[pos] = acc;
}

extern "C" void kernel_launch(void* const* d_in, const int* in_sizes, int n_in,
                              void* d_out, int out_size, void* d_ws, size_t ws_size,
                              hipStream_t stream) {
    const float* cv1 = (const float*)d_in[0];
    const float* cv0 = (const float*)d_in[1];
    const float* sp  = (const float*)d_in[2];
    const float* w0a = (const float*)d_in[3];
    const float* w0b = (const float*)d_in[4];
    const float* w1a = (const float*)d_in[5];
    const float* w1b = (const float*)d_in[6];
    const float* g0  = (const float*)d_in[7];
    const float* g1  = (const float*)d_in[8];
    const float* g2  = (const float*)d_in[9];
    const float* g3  = (const float*)d_in[10];
    const float* b0  = (const float*)d_in[11];
    const float* b1  = (const float*)d_in[12];
    const float* b2  = (const float*)d_in[13];
    const float* b3  = (const float*)d_in[14];

    // Workspace layout (bf16 intermediates, f32 accumulation inside kernels):
    //   x1  @ 0          : 32*196608*2  = 12,582,912 B
    //   x2  @ 12,582,912 : 16*1572864*2 = 50,331,648 B   (ends 62,914,560)
    //   x3  @ 62,914,560 : 50,331,648 B                  (ends 113,246,208)
    //   cost@ 0          : 25,165,824 B  (aliases dead x1 + part of dead x2)
    char* ws = (char*)d_ws;
    bf16* x1   = (bf16*)(ws);
    bf16* x2   = (bf16*)(ws + 12582912);
    bf16* x3   = (bf16*)(ws + 62914560);
    bf16* cost = (bf16*)(ws);

    kA<<<768,   256, 0, stream>>>(cv1, w0a, g0, b0, x1);
    kB<<<6144,  256, 0, stream>>>(x1, w0b, g1, b1, x2);
    kD<<<6144,  256, 0, stream>>>(x2, cv0, w1a, g2, b2, x3);
    kE<<<49152, 256, 0, stream>>>(x3, w1b, g3, b3, cost);
    kF<<<49152, 256, 0, stream>>>(cost, sp, (float*)d_out);
}

// Round 3
// 378.549 us; speedup vs baseline: 1.4457x; 1.4457x over previous
//
#include <hip/hip_runtime.h>
#include <hip/hip_bf16.h>

typedef __hip_bfloat16 bf16;

// Dims
constexpr int cD0 = 24,  cH0 = 64,  cW0 = 128;   // cv1 / x1 spatial
constexpr int cD1 = 48,  cH1 = 128, cW1 = 256;   // x2 / cv0 / x3 spatial
constexpr int cD2 = 96,  cH2 = 256, cW2 = 512;   // cost / out spatial
constexpr size_t PL0 = (size_t)cD0 * cH0 * cW0;  // 196608
constexpr size_t PL1 = (size_t)cD1 * cH1 * cW1;  // 1572864
constexpr size_t PL2 = (size_t)cD2 * cH2 * cW2;  // 12582912

__device__ __forceinline__ float b2f(bf16 v) { return __bfloat162float(v); }
__device__ __forceinline__ bf16  f2b(float v) { return __float2bfloat16(v); }
__device__ __forceinline__ float lrelu(float v) { return v >= 0.f ? v : 0.01f * v; }

// ---------------- Stage A: x1 = bn_lrelu(deconv(cv1, w0a, s1, pad(1,0,0))) ----
__global__ __launch_bounds__(256) void kA(const float* __restrict__ cv1,
                                          const float* __restrict__ w0a,
                                          const float* __restrict__ g0,
                                          const float* __restrict__ b0,
                                          bf16* __restrict__ x1) {
    __shared__ float lw[3][32][32];   // [u][ci][co] — all lanes read same addr (broadcast)
    __shared__ float lsc[32], lbi[32];
    const int tid = threadIdx.x;
    for (int i = tid; i < 32 * 32 * 3; i += 256) {
        int ci = i / 96, r = i - ci * 96, co = r / 3, u = r - co * 3;
        lw[u][ci][co] = w0a[i];
    }
    if (tid < 32) {
        lsc[tid] = g0[tid] * (1.0f / sqrtf(1.0f + 1e-5f));
        lbi[tid] = b0[tid];
    }
    __syncthreads();

    const int pos = blockIdx.x * 256 + tid;        // 196608 total
    const int x = pos & (cW0 - 1);
    const int y = (pos >> 7) & (cH0 - 1);
    const int z = pos >> 13;

    float acc[32];
    #pragma unroll
    for (int co = 0; co < 32; ++co) acc[co] = 0.f;

    #pragma unroll
    for (int u = 0; u < 3; ++u) {
        const int zi = z + 1 - u;
        if (zi < 0 || zi >= cD0) continue;
        const float* src = cv1 + (size_t)(zi * cH0 + y) * cW0 + x;
        for (int ci = 0; ci < 32; ++ci) {
            const float v = src[ci * PL0];
            const float4* wp = (const float4*)&lw[u][ci][0];
            #pragma unroll
            for (int q = 0; q < 8; ++q) {
                float4 wv = wp[q];
                acc[4*q+0] += v * wv.x; acc[4*q+1] += v * wv.y;
                acc[4*q+2] += v * wv.z; acc[4*q+3] += v * wv.w;
            }
        }
    }
    #pragma unroll
    for (int co = 0; co < 32; ++co)
        x1[co * PL0 + (size_t)(z * cH0 + y) * cW0 + x] =
            f2b(lrelu(acc[co] * lsc[co] + lbi[co]));
}

// ---------------- Stage B: x2 = bn_lrelu(deconv(x1, w0b, s2, pad(1,0,0))) ----
// One wave handles one full output row (od,oh): lane computes ow = lane+{0,64,128,192}
// (same kw parity, so weight regs are reused 4x). LDS layout puts kw at stride 16
// floats so the two kw lane-groups hit disjoint bank quads (conflict-free).
__global__ __launch_bounds__(256) void kB(const bf16* __restrict__ x1,
                                          const float* __restrict__ w0b,
                                          const float* __restrict__ g1,
                                          const float* __restrict__ b1,
                                          bf16* __restrict__ x2) {
    __shared__ float lw[4][2][32][2][16];   // [kd][kh][ci][kw][co]
    __shared__ float lsc[16], lbi[16];
    const int tid = threadIdx.x;
    for (int i = tid; i < 8192; i += 256) {
        // source layout (ci,co,kd,kh,kw): i = ci*256 + co*16 + kd*4 + kh*2 + kw
        int ci = i >> 8, co = (i >> 4) & 15, kd = (i >> 2) & 3, kh = (i >> 1) & 1, kw = i & 1;
        lw[kd][kh][ci][kw][co] = w0b[i];
    }
    if (tid < 16) {
        lsc[tid] = g1[tid] * (1.0f / sqrtf(1.0f + 1e-5f));
        lbi[tid] = b1[tid];
    }
    __syncthreads();

    const int t    = blockIdx.x * 256 + tid;   // 393216 threads (1536 blocks)
    const int lane = t & 63;
    const int row  = t >> 6;                   // 6144 rows = (od,oh)
    const int oh = row & 127, od = row >> 7;
    const int ih = oh >> 1, kh = oh & 1;
    const int kw = lane & 1;
    const int p  = (od + 1) & 1;
    const int iwb = lane >> 1;

    float acc[4][16];
    #pragma unroll
    for (int k = 0; k < 4; ++k)
        #pragma unroll
        for (int co = 0; co < 16; ++co) acc[k][co] = 0.f;

    #pragma unroll
    for (int j = 0; j < 2; ++j) {
        const int kd = p + 2 * j;
        const int id = (od + 1 - kd) >> 1;
        if (id < 0 || id >= cD0) continue;
        const bf16* src = x1 + (size_t)(id * cH0 + ih) * cW0 + iwb;
        for (int ci = 0; ci < 32; ++ci) {
            const float v0 = b2f(src[ci * PL0 +  0]);
            const float v1 = b2f(src[ci * PL0 + 32]);
            const float v2 = b2f(src[ci * PL0 + 64]);
            const float v3 = b2f(src[ci * PL0 + 96]);
            const float4* wp = (const float4*)&lw[kd][kh][ci][kw][0];
            #pragma unroll
            for (int q = 0; q < 4; ++q) {
                float4 wv = wp[q];
                acc[0][4*q+0] += v0 * wv.x; acc[0][4*q+1] += v0 * wv.y;
                acc[0][4*q+2] += v0 * wv.z; acc[0][4*q+3] += v0 * wv.w;
                acc[1][4*q+0] += v1 * wv.x; acc[1][4*q+1] += v1 * wv.y;
                acc[1][4*q+2] += v1 * wv.z; acc[1][4*q+3] += v1 * wv.w;
                acc[2][4*q+0] += v2 * wv.x; acc[2][4*q+1] += v2 * wv.y;
                acc[2][4*q+2] += v2 * wv.z; acc[2][4*q+3] += v2 * wv.w;
                acc[3][4*q+0] += v3 * wv.x; acc[3][4*q+1] += v3 * wv.y;
                acc[3][4*q+2] += v3 * wv.z; acc[3][4*q+3] += v3 * wv.w;
            }
        }
    }
    const size_t obase = (size_t)(od * cH1 + oh) * cW1 + lane;
    #pragma unroll
    for (int k = 0; k < 4; ++k)
        #pragma unroll
        for (int co = 0; co < 16; ++co)
            x2[co * PL1 + obase + 64 * k] =
                f2b(lrelu(acc[k][co] * lsc[co] + lbi[co]));
}

// ---------------- Stage D: x3 = bn_lrelu(deconv(concat(x2,cv0), w1a, s1, pad(1,0,0)))
// One wave per row (z,y); lane computes x = lane+{0,64,128,192}, weights reused 4x.
__global__ __launch_bounds__(256) void kD(const bf16* __restrict__ x2,
                                          const float* __restrict__ cv0,
                                          const float* __restrict__ w1a,
                                          const float* __restrict__ g2,
                                          const float* __restrict__ b2v,
                                          bf16* __restrict__ x3) {
    __shared__ float lw[3][32][16];   // [u][ci][co] — broadcast reads
    __shared__ float lsc[16], lbi[16];
    const int tid = threadIdx.x;
    for (int i = tid; i < 1536; i += 256) {
        int ci = i / 48, r = i - ci * 48, co = r / 3, u = r - co * 3;
        lw[u][ci][co] = w1a[i];
    }
    if (tid < 16) {
        lsc[tid] = g2[tid] * (1.0f / sqrtf(1.0f + 1e-5f));
        lbi[tid] = b2v[tid];
    }
    __syncthreads();

    const int t    = blockIdx.x * 256 + tid;   // 393216 threads (1536 blocks)
    const int lane = t & 63;
    const int row  = t >> 6;                   // 6144 rows = (z,y)
    const int y = row & 127, z = row >> 7;

    float acc[4][16];
    #pragma unroll
    for (int k = 0; k < 4; ++k)
        #pragma unroll
        for (int co = 0; co < 16; ++co) acc[k][co] = 0.f;

    #pragma unroll
    for (int u = 0; u < 3; ++u) {
        const int zi = z + 1 - u;
        if (zi < 0 || zi >= cD1) continue;
        const size_t base = (size_t)(zi * cH1 + y) * cW1 + lane;
        for (int ci = 0; ci < 16; ++ci) {           // channels 0..15 = x2
            const float v0 = b2f(x2[ci * PL1 + base +   0]);
            const float v1 = b2f(x2[ci * PL1 + base +  64]);
            const float v2 = b2f(x2[ci * PL1 + base + 128]);
            const float v3 = b2f(x2[ci * PL1 + base + 192]);
            const float4* wp = (const float4*)&lw[u][ci][0];
            #pragma unroll
            for (int q = 0; q < 4; ++q) {
                float4 wv = wp[q];
                acc[0][4*q+0] += v0 * wv.x; acc[0][4*q+1] += v0 * wv.y;
                acc[0][4*q+2] += v0 * wv.z; acc[0][4*q+3] += v0 * wv.w;
                acc[1][4*q+0] += v1 * wv.x; acc[1][4*q+1] += v1 * wv.y;
                acc[1][4*q+2] += v1 * wv.z; acc[1][4*q+3] += v1 * wv.w;
                acc[2][4*q+0] += v2 * wv.x; acc[2][4*q+1] += v2 * wv.y;
                acc[2][4*q+2] += v2 * wv.z; acc[2][4*q+3] += v2 * wv.w;
                acc[3][4*q+0] += v3 * wv.x; acc[3][4*q+1] += v3 * wv.y;
                acc[3][4*q+2] += v3 * wv.z; acc[3][4*q+3] += v3 * wv.w;
            }
        }
        for (int ci = 0; ci < 16; ++ci) {           // channels 16..31 = cv0
            const float v0 = cv0[ci * PL1 + base +   0];
            const float v1 = cv0[ci * PL1 + base +  64];
            const float v2 = cv0[ci * PL1 + base + 128];
            const float v3 = cv0[ci * PL1 + base + 192];
            const float4* wp = (const float4*)&lw[u][16 + ci][0];
            #pragma unroll
            for (int q = 0; q < 4; ++q) {
                float4 wv = wp[q];
                acc[0][4*q+0] += v0 * wv.x; acc[0][4*q+1] += v0 * wv.y;
                acc[0][4*q+2] += v0 * wv.z; acc[0][4*q+3] += v0 * wv.w;
                acc[1][4*q+0] += v1 * wv.x; acc[1][4*q+1] += v1 * wv.y;
                acc[1][4*q+2] += v1 * wv.z; acc[1][4*q+3] += v1 * wv.w;
                acc[2][4*q+0] += v2 * wv.x; acc[2][4*q+1] += v2 * wv.y;
                acc[2][4*q+2] += v2 * wv.z; acc[2][4*q+3] += v2 * wv.w;
                acc[3][4*q+0] += v3 * wv.x; acc[3][4*q+1] += v3 * wv.y;
                acc[3][4*q+2] += v3 * wv.z; acc[3][4*q+3] += v3 * wv.w;
            }
        }
    }
    const size_t obase = (size_t)(z * cH1 + y) * cW1 + lane;
    #pragma unroll
    for (int k = 0; k < 4; ++k)
        #pragma unroll
        for (int co = 0; co < 16; ++co)
            x3[co * PL1 + obase + 64 * k] =
                f2b(lrelu(acc[k][co] * lsc[co] + lbi[co]));
}

// ---------------- Stage E: cost = bn_lrelu(deconv(x3, w1b, s2, pad(1,0,0))) ----
// One thread computes the 2x2 (oh,ow)-parity quad for one (od,ih,iw): each x3
// load feeds 4 FMAs; the kw-pair packs into one 4B coalesced store.
__global__ __launch_bounds__(256) void kE(const bf16* __restrict__ x3,
                                          const float* __restrict__ w1b,
                                          const float* __restrict__ g3,
                                          const float* __restrict__ b3v,
                                          bf16* __restrict__ cost) {
    __shared__ float lw[256];   // w1b (16,1,4,2,2): i = ci*16 + kd*4 + kh*2 + kw
    const int tid = threadIdx.x;
    lw[tid] = w1b[tid];
    __syncthreads();

    const int t    = blockIdx.x * 256 + tid;   // 3145728 threads (12288 blocks)
    const int lane = t & 63;
    const int rowq = t >> 6;                   // 49152 = 4 * 128 * 96
    const int iw = lane + 64 * (rowq & 3);
    const int ih = (rowq >> 2) & 127;
    const int od = rowq >> 9;
    const int p  = (od + 1) & 1;

    float a00 = 0.f, a01 = 0.f, a10 = 0.f, a11 = 0.f;  // [kh][kw]
    #pragma unroll
    for (int j = 0; j < 2; ++j) {
        const int kd = p + 2 * j;
        const int id = (od + 1 - kd) >> 1;
        if (id < 0 || id >= cD1) continue;
        const size_t base = (size_t)(id * cH1 + ih) * cW1 + iw;
        #pragma unroll
        for (int ci = 0; ci < 16; ++ci) {
            const float v = b2f(x3[ci * PL1 + base]);
            const float* w = &lw[ci * 16 + kd * 4];
            a00 += v * w[0]; a01 += v * w[1];
            a10 += v * w[2]; a11 += v * w[3];
        }
    }
    const float sc = g3[0] * (1.0f / sqrtf(1.0f + 1e-5f));
    const float bi = b3v[0];
    union { uint u; ushort s[2]; } pk;
    const size_t ob = (size_t)(od * cH2 + 2 * ih) * cW2 + 2 * iw;
    pk.s[0] = __bfloat16_as_ushort(f2b(lrelu(a00 * sc + bi)));
    pk.s[1] = __bfloat16_as_ushort(f2b(lrelu(a01 * sc + bi)));
    *(uint*)(cost + ob) = pk.u;
    pk.s[0] = __bfloat16_as_ushort(f2b(lrelu(a10 * sc + bi)));
    pk.s[1] = __bfloat16_as_ushort(f2b(lrelu(a11 * sc + bi)));
    *(uint*)(cost + ob + cW2) = pk.u;
}

// ---------------- Stage F: 9-shift superpixel aggregation --------------------
// out[d,y,x] = Sum_k sp[k,y,x] * cost[d, y-4*(1-r), x-4*(1-c)], OOB -> 0
// One thread handles 4 consecutive d for one (y,x), reusing the 9 sp weights.
__global__ __launch_bounds__(256) void kF(const bf16* __restrict__ cost,
                                          const float* __restrict__ sp,
                                          float* __restrict__ out) {
    const int t    = blockIdx.x * 256 + threadIdx.x;  // 3145728 threads (12288 blocks)
    const int lane = t & 63;
    const int rowq = t >> 6;                  // 49152 = 8 * 256 * 24
    const int x  = lane + 64 * (rowq & 7);
    const int y  = (rowq >> 3) & 255;
    const int d0 = (rowq >> 11) * 4;
    const size_t plane = (size_t)cH2 * cW2;

    float w[9];
    int cyc[3], cxc[3];
    #pragma unroll
    for (int r = 0; r < 3; ++r) {
        const int cy = y - 4 * (1 - r);
        const bool vy = (cy >= 0) && (cy < cH2);
        cyc[r] = vy ? cy : 0;
        #pragma unroll
        for (int c = 0; c < 3; ++c) {
            const int cx = x - 4 * (1 - c);
            const bool vx = (cx >= 0) && (cx < cW2);
            if (c == 0 || r == 0) {}  // no-op
            w[r*3+c] = (vy && vx) ? sp[(size_t)(r*3+c) * plane + (size_t)y * cW2 + x] : 0.f;
            if (r == 0) cxc[c] = vx ? cx : 0;
        }
    }
    #pragma unroll
    for (int dd = 0; dd < 4; ++dd) {
        const int d = d0 + dd;
        const bf16* cp = cost + (size_t)d * plane;
        float acc = 0.f;
        #pragma unroll
        for (int r = 0; r < 3; ++r)
            #pragma unroll
            for (int c = 0; c < 3; ++c)
                acc += w[r*3+c] * b2f(cp[(size_t)cyc[r] * cW2 + cxc[c]]);
        out[(size_t)d * plane + (size_t)y * cW2 + x] = acc;
    }
}

extern "C" void kernel_launch(void* const* d_in, const int* in_sizes, int n_in,
                              void* d_out, int out_size, void* d_ws, size_t ws_size,
                              hipStream_t stream) {
    const float* cv1 = (const float*)d_in[0];
    const float* cv0 = (const float*)d_in[1];
    const float* sp  = (const float*)d_in[2];
    const float* w0a = (const float*)d_in[3];
    const float* w0b = (const float*)d_in[4];
    const float* w1a = (const float*)d_in[5];
    const float* w1b = (const float*)d_in[6];
    const float* g0  = (const float*)d_in[7];
    const float* g1  = (const float*)d_in[8];
    const float* g2  = (const float*)d_in[9];
    const float* g3  = (const float*)d_in[10];
    const float* b0  = (const float*)d_in[11];
    const float* b1  = (const float*)d_in[12];
    const float* b2  = (const float*)d_in[13];
    const float* b3  = (const float*)d_in[14];

    // Workspace layout (bf16 intermediates, f32 accumulation inside kernels):
    //   x1  @ 0          : 12,582,912 B
    //   x2  @ 12,582,912 : 50,331,648 B   (ends 62,914,560)
    //   x3  @ 62,914,560 : 50,331,648 B   (ends 113,246,208)
    //   cost@ 0          : 25,165,824 B   (aliases dead x1 + part of dead x2)
    char* ws = (char*)d_ws;
    bf16* x1   = (bf16*)(ws);
    bf16* x2   = (bf16*)(ws + 12582912);
    bf16* x3   = (bf16*)(ws + 62914560);
    bf16* cost = (bf16*)(ws);

    kA<<<768,   256, 0, stream>>>(cv1, w0a, g0, b0, x1);
    kB<<<1536,  256, 0, stream>>>(x1, w0b, g1, b1, x2);
    kD<<<1536,  256, 0, stream>>>(x2, cv0, w1a, g2, b2, x3);
    kE<<<12288, 256, 0, stream>>>(x3, w1b, g3, b3, cost);
    kF<<<12288, 256, 0, stream>>>(cost, sp, (float*)d_out);
}